// Round 3
// baseline (232.854 us; speedup 1.0000x reference)
//
#include <hip/hip_runtime.h>

// Problem constants
#define NTOK   2048
#define DIM    64
#define NCODES 50000
#define THRESH 100.0f
#define BIG    3.0e38f
#define MARGIN 4.0f      // rigorous 2E bound ~2.5; safety margin absorbs c2 rounding delta
#define NBLK   391       // 128-code MFMA blocks
#define BM32   1564      // 32-code screening blocks (391*4)
#define NCG    128       // code groups: first 7 have 4 blocks, rest 3 (7*4+121*3=391)

typedef __attribute__((ext_vector_type(8)))  __bf16 bf16x8;
typedef __attribute__((ext_vector_type(16))) float  float16;

__device__ __forceinline__ unsigned short f2bf(float f) {
    union { float f; unsigned int u; } v; v.f = f;
    unsigned int r = v.u + 0x7FFF + ((v.u >> 16) & 1);
    return (unsigned short)(r >> 16);
}
__device__ __forceinline__ unsigned int pack2(float a, float b) {
    return (unsigned int)f2bf(a) | ((unsigned int)f2bf(b) << 16);
}
// log-depth max of 16 (pairwise tree; clang fuses into v_max3 chains)
__device__ __forceinline__ float max16(const float16& v) {
    float a = fmaxf(v[0], v[1]),   b = fmaxf(v[2], v[3]);
    float c = fmaxf(v[4], v[5]),   d = fmaxf(v[6], v[7]);
    float e = fmaxf(v[8], v[9]),   f = fmaxf(v[10], v[11]);
    float g = fmaxf(v[12], v[13]), h = fmaxf(v[14], v[15]);
    a = fmaxf(a, b); c = fmaxf(c, d); e = fmaxf(e, f); g = fmaxf(g, h);
    return fmaxf(fmaxf(a, c), fmaxf(e, g));
}

// ---------------------------------------------------------------------------
// Kernel 1 (stage A): bf16 MFMA screening directly from fp32 inputs.
// Output layout: bmB[blk][token] float4 tiles (components = the 4 32-code
// sub-blocks b = blk*4+mi). Epilogue = ONE dwordx4 store per lane; a wave
// writes 1 KB contiguous -> write traffic exactly 12.8 MB AND finalize can
// read per-token tiles as float4 gathers (both sides coalesced; round 1
// token-major scattered stageA writes, round 2 column-major starved finalize).
// Grid: 128 code groups x 8 token supertiles = 1024 WGs at 4 WGs/CU
// (launch_bounds(256,4); 120 VGPR fits the 128 cap) — doubles resident waves
// vs round 2 to hide prefetch latency + conversion VALU.
// gi%8 -> XCD (8 supertile copies of one group share an XCD; 128%8==0 keeps
// the mapping; codes slice per XCD ~1.6 MB, L2-resident).
// ---------------------------------------------------------------------------
__global__ __launch_bounds__(256, 4)
void nn_stageA_kernel(const float* __restrict__ x,
                      const float* __restrict__ codes,
                      float4* __restrict__ bmB) {
    __shared__ __bf16 cs[128 * 72];   // code tile, 144 B row stride
    __shared__ float  c2s[128];       // holds -c2/2 per tile row

    const int tid  = threadIdx.x;
    const int w    = tid >> 6;
    const int lane = tid & 63;
    const int l31  = lane & 31;
    const int h    = lane >> 5;
    const int gi   = blockIdx.x;
    const int g0   = 3 * gi + min(gi, 7);
    const int nb   = (gi < 7) ? 4 : 3;
    const int t0   = blockIdx.y * 256;
    const int row_ = tid >> 3;        // 0..31 within an 'it' stripe
    const int seg  = tid & 7;         // 8 lanes per 64-dim code row

    // B fragments (tokens w*64..w*64+63) from fp32 x, converted in-register.
    bf16x8 bfr[4][2];
#pragma unroll
    for (int s = 0; s < 4; ++s)
#pragma unroll
        for (int nj = 0; nj < 2; ++nj) {
            const float4* xp = (const float4*)(x +
                (size_t)(t0 + w * 64 + nj * 32 + l31) * DIM + s * 16 + h * 8);
            float4 a = xp[0], b = xp[1];
            uint4 u;
            u.x = pack2(a.x, a.y); u.y = pack2(a.z, a.w);
            u.z = pack2(b.x, b.y); u.w = pack2(b.z, b.w);
            bfr[s][nj] = *(bf16x8*)&u;
        }

    // code-tile register prefetch: 128 rows x 256 B fp32; 8 lanes/row, 32 B/lane
    float4 pra[4], prb[4];
    auto prefetch = [&](int blk) {
        int n0 = blk * 128;
#pragma unroll
        for (int it = 0; it < 4; ++it) {
            int n = n0 + it * 32 + row_;
            if (n < NCODES) {
                const float4* cp = (const float4*)(codes + (size_t)n * DIM + seg * 8);
                pra[it] = cp[0]; prb[it] = cp[1];
            } else {
                pra[it] = make_float4(0.f, 0.f, 0.f, 0.f);
                prb[it] = pra[it];
            }
        }
    };
    prefetch(g0);

    for (int t = 0; t < nb; ++t) {
        const int blk = g0 + t;
        __syncthreads();   // previous iter's readers done with cs/c2s

        // convert + store current tile (regs -> LDS, conflict-free writes);
        // c2s gets -c2/2 directly
#pragma unroll
        for (int it = 0; it < 4; ++it) {
            int row = it * 32 + row_;
            float4 a = pra[it], b = prb[it];
            float s = a.x * a.x;
            s = fmaf(a.y, a.y, s); s = fmaf(a.z, a.z, s); s = fmaf(a.w, a.w, s);
            s = fmaf(b.x, b.x, s); s = fmaf(b.y, b.y, s);
            s = fmaf(b.z, b.z, s); s = fmaf(b.w, b.w, s);
            s += __shfl_xor(s, 1);   // 8 seg-lanes hold one row: bits 0-2 of tid
            s += __shfl_xor(s, 2);
            s += __shfl_xor(s, 4);
            uint4 u;
            u.x = pack2(a.x, a.y); u.y = pack2(a.z, a.w);
            u.z = pack2(b.x, b.y); u.w = pack2(b.z, b.w);
            *(uint4*)&cs[row * 72 + seg * 8] = u;
            if (seg == 0)
                c2s[row] = (blk * 128 + row < NCODES) ? -0.5f * s : -0.5f * BIG;
        }
        if (t + 1 < nb) prefetch(blk + 1);   // latency hides under MFMA phase
        __syncthreads();

        // acc[mi][nj][r] = -c2[code_row]/2  (c2s reads are 2-addr broadcasts)
        // C/D: col = lane&31 (token), row = (r&3) + 8*(r>>2) + 4*h (code)
        float16 acc[4][2];
#pragma unroll
        for (int mi = 0; mi < 4; ++mi)
#pragma unroll
            for (int g2 = 0; g2 < 4; ++g2) {
                float4 c4 = *(float4*)&c2s[mi * 32 + g2 * 8 + 4 * h];
#pragma unroll
                for (int i = 0; i < 4; ++i) {
                    float iv = ((float*)&c4)[i];
                    acc[mi][0][g2 * 4 + i] = iv;
                    acc[mi][1][g2 * 4 + i] = iv;
                }
            }

        // K = 64 in 4 steps of 16; A from LDS, B from registers
#pragma unroll
        for (int s = 0; s < 4; ++s) {
            bf16x8 a[4];
#pragma unroll
            for (int mi = 0; mi < 4; ++mi)
                a[mi] = *(bf16x8*)&cs[(mi * 32 + l31) * 72 + s * 16 + h * 8];
#pragma unroll
            for (int mi = 0; mi < 4; ++mi)
#pragma unroll
                for (int nj = 0; nj < 2; ++nj)
                    acc[mi][nj] = __builtin_amdgcn_mfma_f32_32x32x16_bf16(
                        a[mi], bfr[s][nj], acc[mi][nj], 0, 0, 0);
        }

        // epilogue: per-token screen value per 32-code group mi; the 4 mi
        // values for a token live in ONE lane -> single float4 tile store.
        // lanes<32 carry tokens +0..31 (nj=0), lanes>=32 tokens +32..63.
        // (invalid rows carry ~-1.5e38 from -BIG/2 init -> never win the max;
        // an all-invalid group yields +3e38 -> never a candidate)
        float4 o[2];
#pragma unroll
        for (int nj = 0; nj < 2; ++nj)
#pragma unroll
            for (int mi = 0; mi < 4; ++mi) {
                float m = max16(acc[mi][nj]);
                m = fmaxf(m, __shfl_xor(m, 32));  // merge h halves (rows +4)
                ((float*)&o[nj])[mi] = -2.0f * m;
            }
        float4 ov = (lane < 32) ? o[0] : o[1];
        int token = t0 + w * 64 + lane;
        bmB[(size_t)blk * NTOK + token] = ov;   // wave: 1 KB contiguous
    }
}

// ---------------------------------------------------------------------------
// Kernel 2 (finalize): one WG per token (2048 WGs = 8/CU; round 2's 128 WGs
// left half the chip idle at 4.4% occupancy). Token index XCD-swizzled so the
// 8 tokens sharing each 128 B bmB line live on one XCD's L2 (1.6 MB/XCD).
// Each thread loads just 2 float4 blk-tiles (register-resident single pass)
// -> shfl+LDS min-reduce -> threshold -> enqueue 32-code candidates from regs
// -> round-1-verified wave-round-robin exact-fp32 rescore (identical fmaf /
// shfl-pair math, on-the-fly x2/c2; absmax 0 in rounds 1 and 2).
// ---------------------------------------------------------------------------
__global__ __launch_bounds__(256)
void nn_finalize_kernel(const float* __restrict__ x,
                        const float* __restrict__ codes,
                        const float4* __restrict__ bmB,
                        int* __restrict__ out) {
    __shared__ float redf[8];      // [0..3] wave gmin, [4..7] wave best-v
    __shared__ int   redi[4];
    __shared__ int   queue[BM32];
    __shared__ int   qcount;
    __shared__ float gshare;

    const int tid  = threadIdx.x;
    const int w    = tid >> 6;
    const int lane = tid & 63;
    const int bid  = blockIdx.x;
    const int t    = (bid & 7) * 256 + (bid >> 3);   // XCD swizzle (bijective)
    const float4* bp = bmB + t;

    if (tid == 0) qcount = 0;

    // single register-resident pass over the 391 blk-tiles for this token
    float4 v0 = bp[(size_t)tid * NTOK];
    const bool has1 = (tid + 256) < NBLK;
    float4 v1 = has1 ? bp[(size_t)(tid + 256) * NTOK]
                     : make_float4(BIG, BIG, BIG, BIG);

    float g = fminf(fminf(fminf(v0.x, v0.y), fminf(v0.z, v0.w)),
                    fminf(fminf(v1.x, v1.y), fminf(v1.z, v1.w)));
#pragma unroll
    for (int m = 1; m < 64; m <<= 1) g = fminf(g, __shfl_xor(g, m));
    if (lane == 0) redf[w] = g;
    __syncthreads();
    if (tid == 0)
        gshare = fminf(fminf(redf[0], redf[1]), fminf(redf[2], redf[3])) + MARGIN;
    __syncthreads();
    const float th = gshare;

    // enqueue candidate 32-code blocks from registers (order irrelevant —
    // final (v,id) total order is deterministic)
    {
        const float* f0 = (const float*)&v0;
#pragma unroll
        for (int c = 0; c < 4; ++c)
            if (f0[c] <= th) queue[atomicAdd(&qcount, 1)] = tid * 4 + c;
        if (has1) {
            const float* f1 = (const float*)&v1;
#pragma unroll
            for (int c = 0; c < 4; ++c)
                if (f1[c] <= th) queue[atomicAdd(&qcount, 1)] = (tid + 256) * 4 + c;
        }
    }
    __syncthreads();
    const int nq = qcount;

    // per-lane x half-row (half = lane&1 -> dims [0,32) or [32,64))
    const int half = lane & 1;
    float4 xh[8];
#pragma unroll
    for (int q = 0; q < 8; ++q)
        xh[q] = *(const float4*)(x + (size_t)t * DIM + half * 32 + q * 4);
    float x2v = 0.f;
#pragma unroll
    for (int q = 0; q < 8; ++q) {
        x2v = fmaf(xh[q].x, xh[q].x, x2v);
        x2v = fmaf(xh[q].y, xh[q].y, x2v);
        x2v = fmaf(xh[q].z, xh[q].z, x2v);
        x2v = fmaf(xh[q].w, xh[q].w, x2v);
    }
    x2v += __shfl_xor(x2v, 1);   // full ||x||^2 in both pair lanes

    float bv = BIG;
    int   bi = 0x7fffffff;
    for (int e = w; e < nq; e += 4) {
        int blk = queue[e];
        int n = blk * 32 + (lane >> 1);
        if (n < NCODES) {   // pair-uniform predicate
            const float4* cp = (const float4*)(codes + (size_t)n * DIM + half * 32);
            float d = 0.f, cq = 0.f;
#pragma unroll
            for (int q = 0; q < 8; ++q) {
                float4 c4 = cp[q];
                d  = fmaf(xh[q].x, c4.x, d);
                d  = fmaf(xh[q].y, c4.y, d);
                d  = fmaf(xh[q].z, c4.z, d);
                d  = fmaf(xh[q].w, c4.w, d);
                cq = fmaf(c4.x, c4.x, cq);
                cq = fmaf(c4.y, c4.y, cq);
                cq = fmaf(c4.z, c4.z, cq);
                cq = fmaf(c4.w, c4.w, cq);
            }
            d  += __shfl_xor(d, 1);    // full 64-dim dot in both pair lanes
            cq += __shfl_xor(cq, 1);   // full ||c||^2 in both pair lanes
            float d2 = fmaxf(fmaf(-2.f, d, x2v + cq), 0.f);
            if (d2 < bv || (d2 == bv && n < bi)) { bv = d2; bi = n; }
        }
    }
#pragma unroll
    for (int m = 1; m < 64; m <<= 1) {
        float vv = __shfl_xor(bv, m);
        int   ii = __shfl_xor(bi, m);
        if (vv < bv || (vv == bv && ii < bi)) { bv = vv; bi = ii; }
    }
    if (lane == 0) { redf[4 + w] = bv; redi[w] = bi; }
    __syncthreads();
    if (tid == 0) {
        float fb = BIG;
        int   fi = 0x7fffffff;
#pragma unroll
        for (int i = 0; i < 4; ++i) {
            float vv = redf[4 + i];
            int   ii = redi[i];
            if (vv < fb || (vv == fb && ii < fi)) { fb = vv; fi = ii; }
        }
        out[t] = (fb <= THRESH) ? fi : -1;
    }
}

// ---------------------------------------------------------------------------
// Workspace: bmB[391][2048] float4 tiles (~12.8 MB), block-major tiled.
// ---------------------------------------------------------------------------
extern "C" void kernel_launch(void* const* d_in, const int* in_sizes, int n_in,
                              void* d_out, int out_size, void* d_ws, size_t ws_size,
                              hipStream_t stream) {
    const float* x     = (const float*)d_in[0];  // [2,1024,64]
    const float* codes = (const float*)d_in[1];  // [50000,64]
    float4* bmB = (float4*)d_ws;
    int* out = (int*)d_out;

    nn_stageA_kernel<<<dim3(NCG, 8), 256, 0, stream>>>(x, codes, bmB);
    nn_finalize_kernel<<<NTOK, 256, 0, stream>>>(x, codes, bmB, out);
}

// Round 4
// 130.195 us; speedup vs baseline: 1.7885x; 1.7885x over previous
//
#include <hip/hip_runtime.h>

// Problem constants
#define NTOK   2048
#define DIM    64
#define NCODES 50000
#define THRESH 100.0f
#define BIG    3.0e38f
#define MARGIN 4.0f      // rigorous 2E bound ~2.5; safety margin absorbs c2 rounding delta
#define NBLK   391       // 128-code MFMA blocks
#define BM32   1564      // 32-code screening blocks (391*4)
#define NCG    128       // code groups: first 7 have 4 blocks, rest 3 (7*4+121*3=391)

typedef __attribute__((ext_vector_type(8)))  __bf16 bf16x8;
typedef __attribute__((ext_vector_type(16))) float  float16;

__device__ __forceinline__ unsigned short f2bf(float f) {
    union { float f; unsigned int u; } v; v.f = f;
    unsigned int r = v.u + 0x7FFF + ((v.u >> 16) & 1);
    return (unsigned short)(r >> 16);
}
__device__ __forceinline__ unsigned int pack2(float a, float b) {
    return (unsigned int)f2bf(a) | ((unsigned int)f2bf(b) << 16);
}
// log-depth max of 16 (pairwise tree; clang fuses into v_max3 chains)
__device__ __forceinline__ float max16(const float16& v) {
    float a = fmaxf(v[0], v[1]),   b = fmaxf(v[2], v[3]);
    float c = fmaxf(v[4], v[5]),   d = fmaxf(v[6], v[7]);
    float e = fmaxf(v[8], v[9]),   f = fmaxf(v[10], v[11]);
    float g = fmaxf(v[12], v[13]), h = fmaxf(v[14], v[15]);
    a = fmaxf(a, b); c = fmaxf(c, d); e = fmaxf(e, f); g = fmaxf(g, h);
    return fmaxf(fmaxf(a, c), fmaxf(e, g));
}

// ---------------------------------------------------------------------------
// Kernel 1 (stage A): bf16 MFMA screening directly from fp32 inputs.
// Output layout: bmB[blk][token] float4 tiles (components = the 4 32-code
// sub-blocks b = blk*4+mi). Epilogue = ONE dwordx4 store per lane; a wave
// writes 1 KB contiguous -> write traffic exactly 12.8 MB AND finalize reads
// per-token tiles as float4 gathers (both sides coalesced).
// __launch_bounds__(256, 2): round 3 used (256,4) which capped the kernel at
// 64 VGPRs — acc[4][2] float16 alone is 128 regs — and spilled ~550 MB of
// scratch traffic to HBM (FETCH 214 MB / WRITE 330 MB, 161 us). (256,2)
// compiles this body at 120 VGPR, zero spill (round-2 evidence). At 120 VGPR
// 16 waves/CU still fit -> up to 4 WGs/CU resident with the 1024-WG grid
// (the min-waves arg is an allocator floor, not an occupancy cap).
// Grid: 128 code groups x 8 token supertiles = 1024 WGs.
// gi%8 -> XCD (8 supertile copies of one group share an XCD; 128%8==0 keeps
// the mapping; codes slice per XCD ~1.6 MB, L2-resident).
// ---------------------------------------------------------------------------
__global__ __launch_bounds__(256, 2)
void nn_stageA_kernel(const float* __restrict__ x,
                      const float* __restrict__ codes,
                      float4* __restrict__ bmB) {
    __shared__ __bf16 cs[128 * 72];   // code tile, 144 B row stride
    __shared__ float  c2s[128];       // holds -c2/2 per tile row

    const int tid  = threadIdx.x;
    const int w    = tid >> 6;
    const int lane = tid & 63;
    const int l31  = lane & 31;
    const int h    = lane >> 5;
    const int gi   = blockIdx.x;
    const int g0   = 3 * gi + min(gi, 7);
    const int nb   = (gi < 7) ? 4 : 3;
    const int t0   = blockIdx.y * 256;
    const int row_ = tid >> 3;        // 0..31 within an 'it' stripe
    const int seg  = tid & 7;         // 8 lanes per 64-dim code row

    // B fragments (tokens w*64..w*64+63) from fp32 x, converted in-register.
    bf16x8 bfr[4][2];
#pragma unroll
    for (int s = 0; s < 4; ++s)
#pragma unroll
        for (int nj = 0; nj < 2; ++nj) {
            const float4* xp = (const float4*)(x +
                (size_t)(t0 + w * 64 + nj * 32 + l31) * DIM + s * 16 + h * 8);
            float4 a = xp[0], b = xp[1];
            uint4 u;
            u.x = pack2(a.x, a.y); u.y = pack2(a.z, a.w);
            u.z = pack2(b.x, b.y); u.w = pack2(b.z, b.w);
            bfr[s][nj] = *(bf16x8*)&u;
        }

    // code-tile register prefetch: 128 rows x 256 B fp32; 8 lanes/row, 32 B/lane
    float4 pra[4], prb[4];
    auto prefetch = [&](int blk) {
        int n0 = blk * 128;
#pragma unroll
        for (int it = 0; it < 4; ++it) {
            int n = n0 + it * 32 + row_;
            if (n < NCODES) {
                const float4* cp = (const float4*)(codes + (size_t)n * DIM + seg * 8);
                pra[it] = cp[0]; prb[it] = cp[1];
            } else {
                pra[it] = make_float4(0.f, 0.f, 0.f, 0.f);
                prb[it] = pra[it];
            }
        }
    };
    prefetch(g0);

    for (int t = 0; t < nb; ++t) {
        const int blk = g0 + t;
        __syncthreads();   // previous iter's readers done with cs/c2s

        // convert + store current tile (regs -> LDS, conflict-free writes);
        // c2s gets -c2/2 directly
#pragma unroll
        for (int it = 0; it < 4; ++it) {
            int row = it * 32 + row_;
            float4 a = pra[it], b = prb[it];
            float s = a.x * a.x;
            s = fmaf(a.y, a.y, s); s = fmaf(a.z, a.z, s); s = fmaf(a.w, a.w, s);
            s = fmaf(b.x, b.x, s); s = fmaf(b.y, b.y, s);
            s = fmaf(b.z, b.z, s); s = fmaf(b.w, b.w, s);
            s += __shfl_xor(s, 1);   // 8 seg-lanes hold one row: bits 0-2 of tid
            s += __shfl_xor(s, 2);
            s += __shfl_xor(s, 4);
            uint4 u;
            u.x = pack2(a.x, a.y); u.y = pack2(a.z, a.w);
            u.z = pack2(b.x, b.y); u.w = pack2(b.z, b.w);
            *(uint4*)&cs[row * 72 + seg * 8] = u;
            if (seg == 0)
                c2s[row] = (blk * 128 + row < NCODES) ? -0.5f * s : -0.5f * BIG;
        }
        if (t + 1 < nb) prefetch(blk + 1);   // latency hides under MFMA phase
        __syncthreads();

        // acc[mi][nj][r] = -c2[code_row]/2  (c2s reads are 2-addr broadcasts)
        // C/D: col = lane&31 (token), row = (r&3) + 8*(r>>2) + 4*h (code)
        float16 acc[4][2];
#pragma unroll
        for (int mi = 0; mi < 4; ++mi)
#pragma unroll
            for (int g2 = 0; g2 < 4; ++g2) {
                float4 c4 = *(float4*)&c2s[mi * 32 + g2 * 8 + 4 * h];
#pragma unroll
                for (int i = 0; i < 4; ++i) {
                    float iv = ((float*)&c4)[i];
                    acc[mi][0][g2 * 4 + i] = iv;
                    acc[mi][1][g2 * 4 + i] = iv;
                }
            }

        // K = 64 in 4 steps of 16; A from LDS, B from registers
#pragma unroll
        for (int s = 0; s < 4; ++s) {
            bf16x8 a[4];
#pragma unroll
            for (int mi = 0; mi < 4; ++mi)
                a[mi] = *(bf16x8*)&cs[(mi * 32 + l31) * 72 + s * 16 + h * 8];
#pragma unroll
            for (int mi = 0; mi < 4; ++mi)
#pragma unroll
                for (int nj = 0; nj < 2; ++nj)
                    acc[mi][nj] = __builtin_amdgcn_mfma_f32_32x32x16_bf16(
                        a[mi], bfr[s][nj], acc[mi][nj], 0, 0, 0);
        }

        // epilogue: per-token screen value per 32-code group mi; the 4 mi
        // values for a token live in ONE lane -> single float4 tile store.
        // lanes<32 carry tokens +0..31 (nj=0), lanes>=32 tokens +32..63.
        // (invalid rows carry ~-1.5e38 from -BIG/2 init -> never win the max;
        // an all-invalid group yields +3e38 -> never a candidate)
        float4 o[2];
#pragma unroll
        for (int nj = 0; nj < 2; ++nj)
#pragma unroll
            for (int mi = 0; mi < 4; ++mi) {
                float m = max16(acc[mi][nj]);
                m = fmaxf(m, __shfl_xor(m, 32));  // merge h halves (rows +4)
                ((float*)&o[nj])[mi] = -2.0f * m;
            }
        float4 ov = (lane < 32) ? o[0] : o[1];
        int token = t0 + w * 64 + lane;
        bmB[(size_t)blk * NTOK + token] = ov;   // wave: 1 KB contiguous
    }
}

// ---------------------------------------------------------------------------
// Kernel 2 (finalize): one WG per token (2048 WGs). Token index XCD-swizzled
// so the 8 tokens sharing each 128 B bmB line live on one XCD's L2.
// Each thread loads just 2 float4 blk-tiles (register-resident single pass)
// -> shfl+LDS min-reduce -> threshold -> enqueue 32-code candidates from regs
// -> wave-round-robin exact-fp32 rescore (identical fmaf / shfl-pair math,
// on-the-fly x2/c2; absmax 0 in rounds 1-3).
// ---------------------------------------------------------------------------
__global__ __launch_bounds__(256)
void nn_finalize_kernel(const float* __restrict__ x,
                        const float* __restrict__ codes,
                        const float4* __restrict__ bmB,
                        int* __restrict__ out) {
    __shared__ float redf[8];      // [0..3] wave gmin, [4..7] wave best-v
    __shared__ int   redi[4];
    __shared__ int   queue[BM32];
    __shared__ int   qcount;
    __shared__ float gshare;

    const int tid  = threadIdx.x;
    const int w    = tid >> 6;
    const int lane = tid & 63;
    const int bid  = blockIdx.x;
    const int t    = (bid & 7) * 256 + (bid >> 3);   // XCD swizzle (bijective)
    const float4* bp = bmB + t;

    if (tid == 0) qcount = 0;

    // single register-resident pass over the 391 blk-tiles for this token
    float4 v0 = bp[(size_t)tid * NTOK];
    const bool has1 = (tid + 256) < NBLK;
    float4 v1 = has1 ? bp[(size_t)(tid + 256) * NTOK]
                     : make_float4(BIG, BIG, BIG, BIG);

    float g = fminf(fminf(fminf(v0.x, v0.y), fminf(v0.z, v0.w)),
                    fminf(fminf(v1.x, v1.y), fminf(v1.z, v1.w)));
#pragma unroll
    for (int m = 1; m < 64; m <<= 1) g = fminf(g, __shfl_xor(g, m));
    if (lane == 0) redf[w] = g;
    __syncthreads();
    if (tid == 0)
        gshare = fminf(fminf(redf[0], redf[1]), fminf(redf[2], redf[3])) + MARGIN;
    __syncthreads();
    const float th = gshare;

    // enqueue candidate 32-code blocks from registers (order irrelevant —
    // final (v,id) total order is deterministic)
    {
        const float* f0 = (const float*)&v0;
#pragma unroll
        for (int c = 0; c < 4; ++c)
            if (f0[c] <= th) queue[atomicAdd(&qcount, 1)] = tid * 4 + c;
        if (has1) {
            const float* f1 = (const float*)&v1;
#pragma unroll
            for (int c = 0; c < 4; ++c)
                if (f1[c] <= th) queue[atomicAdd(&qcount, 1)] = (tid + 256) * 4 + c;
        }
    }
    __syncthreads();
    const int nq = qcount;

    // per-lane x half-row (half = lane&1 -> dims [0,32) or [32,64))
    const int half = lane & 1;
    float4 xh[8];
#pragma unroll
    for (int q = 0; q < 8; ++q)
        xh[q] = *(const float4*)(x + (size_t)t * DIM + half * 32 + q * 4);
    float x2v = 0.f;
#pragma unroll
    for (int q = 0; q < 8; ++q) {
        x2v = fmaf(xh[q].x, xh[q].x, x2v);
        x2v = fmaf(xh[q].y, xh[q].y, x2v);
        x2v = fmaf(xh[q].z, xh[q].z, x2v);
        x2v = fmaf(xh[q].w, xh[q].w, x2v);
    }
    x2v += __shfl_xor(x2v, 1);   // full ||x||^2 in both pair lanes

    float bv = BIG;
    int   bi = 0x7fffffff;
    for (int e = w; e < nq; e += 4) {
        int blk = queue[e];
        int n = blk * 32 + (lane >> 1);
        if (n < NCODES) {   // pair-uniform predicate
            const float4* cp = (const float4*)(codes + (size_t)n * DIM + half * 32);
            float d = 0.f, cq = 0.f;
#pragma unroll
            for (int q = 0; q < 8; ++q) {
                float4 c4 = cp[q];
                d  = fmaf(xh[q].x, c4.x, d);
                d  = fmaf(xh[q].y, c4.y, d);
                d  = fmaf(xh[q].z, c4.z, d);
                d  = fmaf(xh[q].w, c4.w, d);
                cq = fmaf(c4.x, c4.x, cq);
                cq = fmaf(c4.y, c4.y, cq);
                cq = fmaf(c4.z, c4.z, cq);
                cq = fmaf(c4.w, c4.w, cq);
            }
            d  += __shfl_xor(d, 1);    // full 64-dim dot in both pair lanes
            cq += __shfl_xor(cq, 1);   // full ||c||^2 in both pair lanes
            float d2 = fmaxf(fmaf(-2.f, d, x2v + cq), 0.f);
            if (d2 < bv || (d2 == bv && n < bi)) { bv = d2; bi = n; }
        }
    }
#pragma unroll
    for (int m = 1; m < 64; m <<= 1) {
        float vv = __shfl_xor(bv, m);
        int   ii = __shfl_xor(bi, m);
        if (vv < bv || (vv == bv && ii < bi)) { bv = vv; bi = ii; }
    }
    if (lane == 0) { redf[4 + w] = bv; redi[w] = bi; }
    __syncthreads();
    if (tid == 0) {
        float fb = BIG;
        int   fi = 0x7fffffff;
#pragma unroll
        for (int i = 0; i < 4; ++i) {
            float vv = redf[4 + i];
            int   ii = redi[i];
            if (vv < fb || (vv == fb && ii < fi)) { fb = vv; fi = ii; }
        }
        out[t] = (fb <= THRESH) ? fi : -1;
    }
}

// ---------------------------------------------------------------------------
// Workspace: bmB[391][2048] float4 tiles (~12.8 MB), block-major tiled.
// ---------------------------------------------------------------------------
extern "C" void kernel_launch(void* const* d_in, const int* in_sizes, int n_in,
                              void* d_out, int out_size, void* d_ws, size_t ws_size,
                              hipStream_t stream) {
    const float* x     = (const float*)d_in[0];  // [2,1024,64]
    const float* codes = (const float*)d_in[1];  // [50000,64]
    float4* bmB = (float4*)d_ws;
    int* out = (int*)d_out;

    nn_stageA_kernel<<<dim3(NCG, 8), 256, 0, stream>>>(x, codes, bmB);
    nn_finalize_kernel<<<NTOK, 256, 0, stream>>>(x, codes, bmB, out);
}